// Round 10
// baseline (86.167 us; speedup 1.0000x reference)
//
#include <hip/hip_runtime.h>
#include <math.h>

#define B_ 8
#define T_ 2048
#define C_ 1024
#define H_ 128

#define TQA 32           // q rows per attention block (2 row-groups x 16)

#define GM 64            // gemm M-tile
#define GN 128           // gemm N-tile
#define GK 64            // gemm K-tile

typedef __attribute__((ext_vector_type(8))) short s16x8;
typedef __attribute__((ext_vector_type(4))) float f32x4;
typedef __attribute__((ext_vector_type(8))) _Float16 f16x8;
typedef __attribute__((ext_vector_type(4))) _Float16 f16x4;

// ---------------------------------------------------------------------------
// Kernel 0: W prep — transpose W[k][h] (q,k,v) into Wtf[n][k] fp16.
// ---------------------------------------------------------------------------
__global__ __launch_bounds__(256) void wprep(
    const float* __restrict__ Wq, const float* __restrict__ Wk,
    const float* __restrict__ Wv, _Float16* __restrict__ Wtf)
{
    const int n   = blockIdx.x;           // 0..383
    const int mat = n >> 7;
    const int h   = n & 127;
    const float* W = (mat == 0) ? Wq : (mat == 1) ? Wk : Wv;
    for (int k = threadIdx.x; k < C_; k += 256)
        Wtf[(size_t)n * C_ + k] = (_Float16)W[(size_t)k * H_ + h];
}

// ---------------------------------------------------------------------------
// Kernel 1: 2-term fp16 MFMA GEMM (unchanged from round 8).
// ---------------------------------------------------------------------------
__global__ __launch_bounds__(256, 3) void gemm_proj(
    const float* __restrict__ x,
    const _Float16* __restrict__ Wtf,
    const float* __restrict__ bq, const float* __restrict__ bk,
    const float* __restrict__ bv,
    _Float16* __restrict__ qg, _Float16* __restrict__ kg,
    _Float16* __restrict__ vg)
{
    __shared__ _Float16 Ah[GM * GK];      // 8 KB
    __shared__ _Float16 Al[GM * GK];      // 8 KB
    __shared__ _Float16 Bf[GN * GK];      // 16 KB

    const int tid  = threadIdx.x;
    const int my   = blockIdx.y;
    const long m0  = (long)blockIdx.x * GM;
    const int lane = tid & 63;
    const int w    = tid >> 6;
    const int wr   = w >> 1, wc = w & 1;
    const int lg   = lane >> 4, lc = lane & 15;

    float4 xr[4];

    #define LOAD_X(k0)                                                        \
        _Pragma("unroll")                                                     \
        for (int it = 0; it < 4; ++it) {                                      \
            const int i  = tid + it * 256;                                    \
            const int r  = i >> 4;                                            \
            const int k4 = i & 15;                                            \
            xr[it] = *(const float4*)&x[(m0 + r) * C_ + (k0) + k4 * 4];       \
        }

    #define STORE_LDS(k0)                                                     \
        _Pragma("unroll")                                                     \
        for (int it = 0; it < 4; ++it) {                                      \
            const int i  = tid + it * 256;                                    \
            const int r  = i >> 4;                                            \
            const int k4 = i & 15;                                            \
            f16x4 hi4, lo4;                                                   \
            _Pragma("unroll")                                                 \
            for (int j = 0; j < 4; ++j) {                                     \
                const float f = ((const float*)&xr[it])[j];                   \
                const _Float16 h16 = (_Float16)f;                             \
                hi4[j] = h16;                                                 \
                lo4[j] = (_Float16)(f - (float)h16);                          \
            }                                                                 \
            const int off = r * 64 + (((k4 >> 1) ^ (r & 7)) << 3)             \
                          + ((k4 & 1) << 2);                                  \
            *(f16x4*)&Ah[off] = hi4;                                          \
            *(f16x4*)&Al[off] = lo4;                                          \
        }                                                                     \
        _Pragma("unroll")                                                     \
        for (int it = 0; it < 4; ++it) {                                      \
            const int i = tid + it * 256;                                     \
            const int r = i >> 3;                                             \
            const int s = i & 7;                                              \
            const size_t g = (size_t)(my * GN + r) * C_ + (k0) + s * 8;       \
            const int off = r * 64 + ((s ^ (r & 7)) << 3);                    \
            *(f16x8*)&Bf[off] = *(const f16x8*)&Wtf[g];                       \
        }

    f32x4 acc[2][4];
    #pragma unroll
    for (int m = 0; m < 2; ++m)
        #pragma unroll
        for (int n = 0; n < 4; ++n) acc[m][n] = (f32x4){0.f, 0.f, 0.f, 0.f};

    LOAD_X(0);
    STORE_LDS(0);
    __syncthreads();

    for (int kt = 0; kt < C_ / GK; ++kt) {
        if (kt < C_ / GK - 1) LOAD_X((kt + 1) * GK);

        #pragma unroll
        for (int kc = 0; kc < 2; ++kc) {
            f16x8 afh[2], afl[2], bf[4];
            #pragma unroll
            for (int m = 0; m < 2; ++m) {
                const int r = wr * 32 + m * 16 + lc;
                const int off = r * 64 + ((((kc << 2) + lg) ^ (r & 7)) << 3);
                afh[m] = *(const f16x8*)&Ah[off];
                afl[m] = *(const f16x8*)&Al[off];
            }
            #pragma unroll
            for (int n = 0; n < 4; ++n) {
                const int r = wc * 64 + n * 16 + lc;
                const int off = r * 64 + ((((kc << 2) + lg) ^ (r & 7)) << 3);
                bf[n] = *(const f16x8*)&Bf[off];
            }
            #pragma unroll
            for (int m = 0; m < 2; ++m)
                #pragma unroll
                for (int n = 0; n < 4; ++n) {
                    acc[m][n] = __builtin_amdgcn_mfma_f32_16x16x32_f16(afh[m], bf[n], acc[m][n], 0, 0, 0);
                    acc[m][n] = __builtin_amdgcn_mfma_f32_16x16x32_f16(afl[m], bf[n], acc[m][n], 0, 0, 0);
                }
        }
        __syncthreads();
        if (kt < C_ / GK - 1) {
            STORE_LDS((kt + 1) * GK);
            __syncthreads();
        }
    }

    const float* bias = (my == 0) ? bq : (my == 1) ? bk : bv;
    _Float16* og = (my == 0) ? qg : (my == 1) ? kg : vg;

    #pragma unroll
    for (int n = 0; n < 4; ++n) {
        const int h = wc * 64 + n * 16 + lc;
        const float bv_ = bias[h];
        #pragma unroll
        for (int m = 0; m < 2; ++m) {
            #pragma unroll
            for (int rr = 0; rr < 4; ++rr) {
                const long row = m0 + wr * 32 + m * 16 + lg * 4 + rr;
                og[(size_t)row * H_ + h] = (_Float16)(acc[m][n][rr] + bv_);
            }
        }
    }
}

// ---------------------------------------------------------------------------
// Kernel 1b: vtrans — vg [B][T][H] -> vtg [B][H][T] (fp16 bits via short).
// ---------------------------------------------------------------------------
__global__ __launch_bounds__(256) void vtrans(
    const short* __restrict__ vh, short* __restrict__ vtg)
{
    __shared__ short tbuf[64][72];
    const int b  = blockIdx.z;
    const int t0 = blockIdx.x * 64;
    const int h0 = blockIdx.y * 64;
    const int tid = threadIdx.x;
    const size_t bo  = (size_t)b * T_ * H_;
    const size_t vbo = (size_t)b * H_ * T_;

    #pragma unroll
    for (int it = 0; it < 2; ++it) {
        const int u = tid + it * 256;
        const int r = u >> 3, c8 = u & 7;
        *(s16x8*)&tbuf[r][c8 * 8] =
            *(const s16x8*)&vh[bo + (size_t)(t0 + r) * H_ + h0 + c8 * 8];
    }
    __syncthreads();
    #pragma unroll
    for (int it = 0; it < 2; ++it) {
        const int u = tid + it * 256;
        const int t8 = u >> 6, hr = u & 63;
        s16x8 v;
        #pragma unroll
        for (int j = 0; j < 8; ++j) v[j] = tbuf[t8 * 8 + j][hr];
        *(s16x8*)&vtg[vbo + (size_t)(h0 + hr) * T_ + t0 + t8 * 8] = v;
    }
}

// ---------------------------------------------------------------------------
// Kernel 2: causal flash attention v6 — swapped QK^T + IN-REGISTER P:
// sfr[ct][rr] = P[qrow=lc][key=ct*16+lg*4+rr] is EXACTLY the A-fragment of
// mfma_f32_16x16x16f16 (row=lc, k=lg*4+j) -> PV needs no LDS round-trip.
// V-read slot: stored group s holds keys (s^((hh>>1)&7))*8; needed group
// a = kp*4 + ct*2 + (lg>>1)  [kp*4 term was the round-9 bug].
// ---------------------------------------------------------------------------
__global__ __launch_bounds__(256, 2) void attn_v6(
    const _Float16* __restrict__ qg, const _Float16* __restrict__ kg,
    const _Float16* __restrict__ vtg, float* __restrict__ out)
{
    __shared__ __align__(16) short Kbuf[2][64 * 128];   // 32 KB
    __shared__ __align__(16) short Vbuf[2][128 * 64];   // 32 KB

    float* Ocmb = (float*)&Kbuf[0][0];   // [32][132] floats (aliased)
    float* Mcmb = (float*)&Vbuf[0][0];   // [32][2]   floats (aliased)

    const int tid  = threadIdx.x;
    const int lane = tid & 63;
    const int w    = tid >> 6;
    const int rg   = w >> 1;
    const int kp   = w & 1;
    const int lg   = lane >> 4;
    const int lc   = lane & 15;
    const int wg   = blockIdx.x;
    const int rank = wg >> 3;
    const int tile = (rank < 32) ? (63 - rank) : (rank - 32);
    const int b    = wg & 7;
    const int t0   = tile * TQA;

    const size_t bo  = (size_t)b * T_ * H_;
    const size_t vbo = (size_t)b * H_ * T_;

    f16x8 qf[4];
    {
        const size_t qbase = bo + (size_t)(t0 + rg * 16 + lc) * H_;
        #pragma unroll
        for (int kc = 0; kc < 4; ++kc)
            qf[kc] = *(const f16x8*)(qg + qbase + kc * 32 + lg * 8);
    }

    f32x4 Oacc[8];
    #pragma unroll
    for (int ht = 0; ht < 8; ++ht) Oacc[ht] = (f32x4){0.f, 0.f, 0.f, 0.f};
    float m_run = -INFINITY;
    float l_run = 0.f;                    // lane-partial (this lane's keys)

    const int nt = tile + 1;
    const int R  = (nt + 1) >> 1;

    f16x8 pf[8];

    #define ISSUE_ST(rs0_)                                                    \
        _Pragma("unroll")                                                     \
        for (int it = 0; it < 8; ++it) {                                      \
            const int c = tid + it * 256;                                     \
            if (c < 1024) {                                                   \
                const int key = c >> 4, slot = c & 15;                        \
                const int hc = slot ^ (key & 7);                              \
                pf[it] = *(const f16x8*)(kg + bo                              \
                          + (size_t)((rs0_) + key) * H_ + hc * 8);            \
            } else {                                                          \
                const int cc = c - 1024;                                      \
                const int hh = cc >> 3, slot = cc & 7;                        \
                const int k8 = slot ^ ((hh >> 1) & 7);                        \
                pf[it] = *(const f16x8*)(vtg + vbo + (size_t)hh * T_          \
                          + (rs0_) + k8 * 8);                                 \
            }                                                                 \
        }

    #define WRITE_ST(bf_)                                                    \
        _Pragma("unroll")                                                     \
        for (int it = 0; it < 8; ++it) {                                      \
            const int c = tid + it * 256;                                     \
            if (c < 1024) {                                                   \
                const int key = c >> 4, slot = c & 15;                        \
                *(f16x8*)&Kbuf[bf_][key * 128 + slot * 8] = pf[it];           \
            } else {                                                          \
                const int cc = c - 1024;                                      \
                const int hh = cc >> 3, slot = cc & 7;                        \
                *(f16x8*)&Vbuf[bf_][hh * 64 + slot * 8] = pf[it];             \
            }                                                                 \
        }

    ISSUE_ST(0);

    for (int r = 0; r < R; ++r) {
        const int bf = r & 1;
        WRITE_ST(bf);
        __syncthreads();
        if (r + 1 < R) ISSUE_ST((r + 1) * 64);

        const int kt = 2 * r + kp;
        if (kt < nt) {
            // ---- S^T = K @ Q^T : two independent accumulator halves ----
            f32x4 sfrA[2], sfrB[2];
            #pragma unroll
            for (int ct = 0; ct < 2; ++ct) {
                sfrA[ct] = (f32x4){0.f, 0.f, 0.f, 0.f};
                sfrB[ct] = (f32x4){0.f, 0.f, 0.f, 0.f};
            }
            #pragma unroll
            for (int kc = 0; kc < 4; ++kc) {
                #pragma unroll
                for (int ct = 0; ct < 2; ++ct) {
                    const int key  = kp * 32 + ct * 16 + lc;
                    const int slot = (kc * 4 + lg) ^ (key & 7);
                    const f16x8 ka = *(const f16x8*)&Kbuf[bf][key * 128 + slot * 8];
                    if (kc < 2)
                        sfrA[ct] = __builtin_amdgcn_mfma_f32_16x16x32_f16(ka, qf[kc], sfrA[ct], 0, 0, 0);
                    else
                        sfrB[ct] = __builtin_amdgcn_mfma_f32_16x16x32_f16(ka, qf[kc], sfrB[ct], 0, 0, 0);
                }
            }
            f32x4 sfr[2];
            #pragma unroll
            for (int ct = 0; ct < 2; ++ct) sfr[ct] = sfrA[ct] + sfrB[ct];

            // ---- causal mask ----
            const int qrow_g = t0 + rg * 16 + lc;
            #pragma unroll
            for (int ct = 0; ct < 2; ++ct) {
                #pragma unroll
                for (int rr = 0; rr < 4; ++rr) {
                    const int key_g = kt * 32 + ct * 16 + lg * 4 + rr;
                    if (key_g > qrow_g) sfr[ct][rr] = -INFINITY;
                }
            }

            // ---- row max (per qrow = lc; reduce across lg groups) ----
            float pmax = sfr[0][0];
            #pragma unroll
            for (int ct = 0; ct < 2; ++ct)
                #pragma unroll
                for (int rr = 0; rr < 4; ++rr) pmax = fmaxf(pmax, sfr[ct][rr]);
            pmax = fmaxf(pmax, __shfl_xor(pmax, 16, 64));
            pmax = fmaxf(pmax, __shfl_xor(pmax, 32, 64));

            // ---- defer-max: rescale only when a new max appears (exact) ----
            if (__any(pmax > m_run)) {
                const float mnew = fmaxf(m_run, pmax);
                const float sc = __expf(m_run - mnew);   // 0 on first tile
                m_run = mnew;
                l_run *= sc;
                float scq[4];
                #pragma unroll
                for (int rr = 0; rr < 4; ++rr)
                    scq[rr] = __shfl(sc, lg * 4 + rr, 64);
                #pragma unroll
                for (int ht = 0; ht < 8; ++ht)
                    #pragma unroll
                    for (int rr = 0; rr < 4; ++rr) Oacc[ht][rr] *= scq[rr];
            }

            // ---- exp + in-lane fp16 pack (P stays in registers) ----
            f16x4 pk[2];
            float lsum = 0.f;
            #pragma unroll
            for (int ct = 0; ct < 2; ++ct)
                #pragma unroll
                for (int rr = 0; rr < 4; ++rr) {
                    const float p = __expf(sfr[ct][rr] - m_run);  // masked->0
                    lsum += p;
                    pk[ct][rr] = (_Float16)p;
                }
            l_run += lsum;

            // ---- PV: A = pk (K=16 layout match), B = V^T b64 reads ----
            #pragma unroll
            for (int ht = 0; ht < 8; ++ht) {
                const int hh = ht * 16 + lc;
                #pragma unroll
                for (int ct = 0; ct < 2; ++ct) {
                    const int slot = (kp * 4 + ct * 2 + (lg >> 1)) ^ ((hh >> 1) & 7);
                    const int addr = hh * 64 + slot * 8 + (lg & 1) * 4;
                    const f16x4 vb = *(const f16x4*)&Vbuf[bf][addr];
                    Oacc[ht] = __builtin_amdgcn_mfma_f32_16x16x16f16(pk[ct], vb, Oacc[ht], 0, 0, 0);
                }
            }
        }
    }

    // ---- finish lane-partial l: sum the 4 lg groups per qrow ----
    l_run += __shfl_xor(l_run, 16, 64);
    l_run += __shfl_xor(l_run, 32, 64);

    __syncthreads();                      // all rounds done before aliasing

    if (kp == 1) {
        #pragma unroll
        for (int ht = 0; ht < 8; ++ht)
            #pragma unroll
            for (int rr = 0; rr < 4; ++rr)
                Ocmb[(size_t)(rg * 16 + lg * 4 + rr) * 132 + ht * 16 + lc] =
                    Oacc[ht][rr];
        if (lg == 0) {
            Mcmb[(rg * 16 + lc) * 2]     = m_run;
            Mcmb[(rg * 16 + lc) * 2 + 1] = l_run;
        }
    }
    __syncthreads();
    if (kp == 0) {
        const float m1 = Mcmb[(rg * 16 + lc) * 2];
        const float l1 = Mcmb[(rg * 16 + lc) * 2 + 1];
        const float M  = fmaxf(m_run, m1);
        const float a0 = __expf(m_run - M);
        const float a1 = __expf(m1 - M);
        const float inv = 1.f / (l_run * a0 + l1 * a1);
        const float f0 = a0 * inv, f1 = a1 * inv;
        float f0q[4], f1q[4];
        #pragma unroll
        for (int rr = 0; rr < 4; ++rr) {
            f0q[rr] = __shfl(f0, lg * 4 + rr, 64);
            f1q[rr] = __shfl(f1, lg * 4 + rr, 64);
        }
        float* ob = out + bo + (size_t)(t0 + rg * 16) * H_;
        #pragma unroll
        for (int ht = 0; ht < 8; ++ht)
            #pragma unroll
            for (int rr = 0; rr < 4; ++rr) {
                const float o1 =
                    Ocmb[(size_t)(rg * 16 + lg * 4 + rr) * 132 + ht * 16 + lc];
                ob[(size_t)(lg * 4 + rr) * H_ + ht * 16 + lc] =
                    Oacc[ht][rr] * f0q[rr] + o1 * f1q[rr];
            }
    }
}

// ---------------------------------------------------------------------------
extern "C" void kernel_launch(void* const* d_in, const int* in_sizes, int n_in,
                              void* d_out, int out_size, void* d_ws, size_t ws_size,
                              hipStream_t stream)
{
    const float* x  = (const float*)d_in[0];
    const float* Wq = (const float*)d_in[1];
    const float* bq = (const float*)d_in[2];
    const float* Wk = (const float*)d_in[3];
    const float* bk = (const float*)d_in[4];
    const float* Wv = (const float*)d_in[5];
    const float* bv = (const float*)d_in[6];
    float* out = (float*)d_out;

    const size_t SZ = (size_t)B_ * T_ * H_;     // 2M elems
    _Float16* qg  = (_Float16*)d_ws;
    _Float16* kg  = qg + SZ;
    _Float16* vg  = kg + SZ;
    _Float16* vtg = vg + SZ;                     // [B][H][T]
    _Float16* Wtf = vtg + SZ;                    // [384][1024]

    wprep<<<dim3(384), dim3(256), 0, stream>>>(Wq, Wk, Wv, Wtf);
    gemm_proj<<<dim3(B_ * T_ / GM, 3), dim3(256), 0, stream>>>(
        x, Wtf, bq, bk, bv, qg, kg, vg);
    vtrans<<<dim3(T_ / 64, H_ / 64, B_), dim3(256), 0, stream>>>(
        (const short*)vg, (short*)vtg);
    attn_v6<<<dim3(512), dim3(256), 0, stream>>>(qg, kg, vtg, out);
}